// Round 2
// baseline (191.140 us; speedup 1.0000x reference)
//
#include <hip/hip_runtime.h>

#define LR 0.01f
#define NSTEPS 100
#define R 4   // rows per thread

// u_{k+1} = a*u_k + c  with a = 1-2*LR*q, c = -LR*p, per element of (B,4).
// R=4 grid-strided rows per thread: all 12 float4 loads issued before any
// compute -> 12 outstanding global_load_dwordx4 per wave (vs 3 serialized
// in R0's 8-VGPR version). Memory-bound floor ~160 MB -> ~25 us @ 6.3 TB/s.
__global__ __launch_bounds__(256) void diffmpc_kernel(
    const float* __restrict__ Q,
    const float* __restrict__ p,
    const float* __restrict__ u0,
    float* __restrict__ out,
    int B)
{
    const int t = blockIdx.x * blockDim.x + threadIdx.x;
    const int nth = gridDim.x * blockDim.x;

    float4 q[R], pr[R], u[R];

    // Issue ALL loads before any dependent compute (12 loads in flight).
#pragma unroll
    for (int r = 0; r < R; ++r) {
        const size_t b = (size_t)t + (size_t)r * nth;
        q[r] = *reinterpret_cast<const float4*>(Q + b * 16 + 12);
    }
#pragma unroll
    for (int r = 0; r < R; ++r) {
        const size_t b = (size_t)t + (size_t)r * nth;
        pr[r] = *reinterpret_cast<const float4*>(p + b * 16 + 12);
    }
#pragma unroll
    for (int r = 0; r < R; ++r) {
        const size_t b = (size_t)t + (size_t)r * nth;
        u[r] = *reinterpret_cast<const float4*>(u0 + b * 4);
    }

    float4 a[R], c[R];
#pragma unroll
    for (int r = 0; r < R; ++r) {
        a[r].x = fmaf(-2.0f * LR, q[r].x, 1.0f);
        a[r].y = fmaf(-2.0f * LR, q[r].y, 1.0f);
        a[r].z = fmaf(-2.0f * LR, q[r].z, 1.0f);
        a[r].w = fmaf(-2.0f * LR, q[r].w, 1.0f);
        c[r].x = -LR * pr[r].x;
        c[r].y = -LR * pr[r].y;
        c[r].z = -LR * pr[r].z;
        c[r].w = -LR * pr[r].w;
    }

#pragma unroll 5
    for (int i = 0; i < NSTEPS; ++i) {
#pragma unroll
        for (int r = 0; r < R; ++r) {
            u[r].x = fmaf(a[r].x, u[r].x, c[r].x);
            u[r].y = fmaf(a[r].y, u[r].y, c[r].y);
            u[r].z = fmaf(a[r].z, u[r].z, c[r].z);
            u[r].w = fmaf(a[r].w, u[r].w, c[r].w);
        }
    }

#pragma unroll
    for (int r = 0; r < R; ++r) {
        const size_t b = (size_t)t + (size_t)r * nth;
        *reinterpret_cast<float4*>(out + b * 4) = u[r];
    }
}

extern "C" void kernel_launch(void* const* d_in, const int* in_sizes, int n_in,
                              void* d_out, int out_size, void* d_ws, size_t ws_size,
                              hipStream_t stream) {
    // Inputs: x_init (B,12) [UNUSED], Q (B,16), p (B,16), u_init (B,4)
    const float* Q  = (const float*)d_in[1];
    const float* p  = (const float*)d_in[2];
    const float* u0 = (const float*)d_in[3];
    float* out = (float*)d_out;

    const int B = in_sizes[3] / 4;          // 1,048,576
    const int block = 256;
    const int threads = B / R;              // exact: B = 2^20, R = 4
    const int grid = threads / block;       // 1,024 blocks

    diffmpc_kernel<<<grid, block, 0, stream>>>(Q, p, u0, out, B);
}

// Round 3
// 187.888 us; speedup vs baseline: 1.0173x; 1.0173x over previous
//
#include <hip/hip_runtime.h>

#define LR 0.01f
#define NSTEPS 100
#define R 2   // rows per thread

// u_{k+1} = a*u_k + c  with a = 1-2*LR*q, c = -LR*p, per element of (B,4).
//
// R2 lesson: without scheduling constraints LLVM interchanges the row/step
// loops to minimize registers (VGPR=32 < the 48 needed for batched a/c/u),
// serializing the loads and making the kernel latency-bound (~1.6 TB/s).
// Fix: issue ALL 3R dwordx4 loads, then __builtin_amdgcn_sched_barrier(0)
// so no compute (and no load sinking) crosses the batch -> 6 loads in
// flight per wave, 32 waves/CU resident.
__global__ __launch_bounds__(256) void diffmpc_kernel(
    const float* __restrict__ Q,
    const float* __restrict__ p,
    const float* __restrict__ u0,
    float* __restrict__ out,
    int nth)
{
    const int t = blockIdx.x * blockDim.x + threadIdx.x;

    float4 q[R], pr[R], u[R];
#pragma unroll
    for (int r = 0; r < R; ++r) {
        const size_t b = (size_t)t + (size_t)r * nth;
        q[r]  = *reinterpret_cast<const float4*>(Q  + b * 16 + 12);
        pr[r] = *reinterpret_cast<const float4*>(p  + b * 16 + 12);
        u[r]  = *reinterpret_cast<const float4*>(u0 + b * 4);
    }
    // Pin the schedule: every load above must be issued before anything below.
    __builtin_amdgcn_sched_barrier(0);

    float4 a[R], c[R];
#pragma unroll
    for (int r = 0; r < R; ++r) {
        a[r].x = fmaf(-2.0f * LR, q[r].x, 1.0f);
        a[r].y = fmaf(-2.0f * LR, q[r].y, 1.0f);
        a[r].z = fmaf(-2.0f * LR, q[r].z, 1.0f);
        a[r].w = fmaf(-2.0f * LR, q[r].w, 1.0f);
        c[r].x = -LR * pr[r].x;
        c[r].y = -LR * pr[r].y;
        c[r].z = -LR * pr[r].z;
        c[r].w = -LR * pr[r].w;
    }

#pragma unroll 5
    for (int i = 0; i < NSTEPS; ++i) {
#pragma unroll
        for (int r = 0; r < R; ++r) {
            u[r].x = fmaf(a[r].x, u[r].x, c[r].x);
            u[r].y = fmaf(a[r].y, u[r].y, c[r].y);
            u[r].z = fmaf(a[r].z, u[r].z, c[r].z);
            u[r].w = fmaf(a[r].w, u[r].w, c[r].w);
        }
    }

#pragma unroll
    for (int r = 0; r < R; ++r) {
        const size_t b = (size_t)t + (size_t)r * nth;
        *reinterpret_cast<float4*>(out + b * 4) = u[r];
    }
}

extern "C" void kernel_launch(void* const* d_in, const int* in_sizes, int n_in,
                              void* d_out, int out_size, void* d_ws, size_t ws_size,
                              hipStream_t stream) {
    // Inputs: x_init (B,12) [UNUSED], Q (B,16), p (B,16), u_init (B,4)
    const float* Q  = (const float*)d_in[1];
    const float* p  = (const float*)d_in[2];
    const float* u0 = (const float*)d_in[3];
    float* out = (float*)d_out;

    const int B = in_sizes[3] / 4;          // 1,048,576
    const int block = 256;
    const int nth = B / R;                  // 524,288 threads (exact)
    const int grid = nth / block;           // 2,048 blocks -> 8,192 waves (32/CU)

    diffmpc_kernel<<<grid, block, 0, stream>>>(Q, p, u0, out, nth);
}

// Round 4
// 186.012 us; speedup vs baseline: 1.0276x; 1.0101x over previous
//
#include <hip/hip_runtime.h>

#define LR 0.01f
#define NSTEPS 100

// u_{k+1} = a*u_k + c with a = 1-2*LR*q, c = -LR*p, per element of (B,4),
// q/p = cols 12..15 of the (B,16) Q/p arrays.
//
// R0-R3 lesson: reading 16 B at stride 64 B (one sector per DRAM burst)
// plateaus at ~1.3 TB/s fetch regardless of batching/occupancy — the address
// pattern is the ceiling. Fix: STREAM Q and p fully contiguously (64 B/lane,
// full-burst efficiency), then redistribute in-register with a fixed wave
// permutation. 160 MB of sequential traffic -> ~27 us @ 6 TB/s.
__global__ __launch_bounds__(256) void diffmpc_kernel(
    const float4* __restrict__ Qv,
    const float4* __restrict__ Pv,
    const float4* __restrict__ Uv,
    float4* __restrict__ Ov)
{
    const int wave = (int)((blockIdx.x * blockDim.x + threadIdx.x) >> 6);
    const int lane = (int)(threadIdx.x & 63);
    const long b0   = (long)wave << 6;   // first row of this wave's 64-row tile
    const long base = b0 * 4;            // tile start, in float4 units

    // Fully-coalesced streaming: 256 consecutive float4s = rows b0..b0+63 of Q.
    float4 q[4], pr[4];
#pragma unroll
    for (int j = 0; j < 4; ++j) q[j]  = Qv[base + j * 64 + lane];
#pragma unroll
    for (int j = 0; j < 4; ++j) pr[j] = Pv[base + j * 64 + lane];
    float4 u = Uv[b0 + lane];            // (B,4) rows: natively coalesced

    // Lane L needs tile-local float4 index 4L+3 (cols 12..15 of row b0+L),
    // which sits in register j = L>>4 of lane (4L+3)&63.
    const int src  = (4 * lane + 3) & 63;
    const int jsel = lane >> 4;
    float4 q4, p4;
#pragma unroll
    for (int j = 0; j < 4; ++j) {
        float4 tq, tp;
        tq.x = __shfl(q[j].x,  src); tq.y = __shfl(q[j].y,  src);
        tq.z = __shfl(q[j].z,  src); tq.w = __shfl(q[j].w,  src);
        tp.x = __shfl(pr[j].x, src); tp.y = __shfl(pr[j].y, src);
        tp.z = __shfl(pr[j].z, src); tp.w = __shfl(pr[j].w, src);
        if (jsel == j) { q4 = tq; p4 = tp; }
    }

    const float ax = fmaf(-2.0f * LR, q4.x, 1.0f);
    const float ay = fmaf(-2.0f * LR, q4.y, 1.0f);
    const float az = fmaf(-2.0f * LR, q4.z, 1.0f);
    const float aw = fmaf(-2.0f * LR, q4.w, 1.0f);
    const float cx = -LR * p4.x;
    const float cy = -LR * p4.y;
    const float cz = -LR * p4.z;
    const float cw = -LR * p4.w;

#pragma unroll 10
    for (int i = 0; i < NSTEPS; ++i) {
        u.x = fmaf(ax, u.x, cx);
        u.y = fmaf(ay, u.y, cy);
        u.z = fmaf(az, u.z, cz);
        u.w = fmaf(aw, u.w, cw);
    }

    Ov[b0 + lane] = u;
}

extern "C" void kernel_launch(void* const* d_in, const int* in_sizes, int n_in,
                              void* d_out, int out_size, void* d_ws, size_t ws_size,
                              hipStream_t stream) {
    // Inputs: x_init (B,12) [UNUSED], Q (B,16), p (B,16), u_init (B,4)
    const float4* Qv = (const float4*)d_in[1];
    const float4* Pv = (const float4*)d_in[2];
    const float4* Uv = (const float4*)d_in[3];
    float4* Ov = (float4*)d_out;

    const int B = in_sizes[3] / 4;   // 1,048,576 rows
    const int waves = B / 64;        // 16,384 waves (exact)
    const int block = 256;           // 4 waves/block
    const int grid = waves / 4;      // 4,096 blocks

    diffmpc_kernel<<<grid, block, 0, stream>>>(Qv, Pv, Uv, Ov);
}